// Round 5
// baseline (5037.156 us; speedup 1.0000x reference)
//
#include <hip/hip_runtime.h>

// Encoder: 2-layer LSTM (H1=64, H2=32, IN=2), B=512, T=4096, + FC [32->16].
// R17: ONE WAVE PER BATCH ELEMENT, ZERO BARRIERS (structural).
//  - A single wave owns BOTH layers of one batch element. Per step-pair the
//    wave interleaves {L1 step tau (chunk c), L2 step tau-64 (chunk c-1)}:
//    two independent serial chains; each fills the other's LDS-latency and
//    dependency bubbles (R16 ran them on separate waves where 1-wave/SIMD
//    left ~65% of the step as unfillable stall).
//  - h1 handoff L1->L2 via a 128-step in-LDS ring, SAME WAVE: ordering is
//    program order + counted lgkmcnt; s_barrier count drops 65 -> 0.
//  - L1 role (all 64 lanes): lane u owns unit u, full K=64 (32 dot8 + x).
//    L2 role: lane=(u=l&31, hf=l>>5), rows (i,f)|(g,o), K=96 (24 dot8),
//    gate exchange via one __shfl_xor(32) pair. Math identical to R16
//    (pre-scaled gates: i/f/o * -log2e, g * -2log2e; same op order).
//  - x staged per 64-step chunk by the same wave (packed fp16, dbuf LDS),
//    global prefetch held in regs across the chunk.
//  - 64-thread blocks, grid 512 (2 blocks/CU). Weights resident: 56 h8.

#define TT 4096
#define BB 512
#define NCH 64   // chunks of 64 steps

typedef float    f4  __attribute__((ext_vector_type(4)));
typedef int      i4  __attribute__((ext_vector_type(4)));
typedef _Float16 h2v __attribute__((ext_vector_type(2)));
typedef _Float16 h8  __attribute__((ext_vector_type(8)));   // 4 VGPRs

__device__ __forceinline__ float fexp2(float x){ return __builtin_amdgcn_exp2f(x); }
__device__ __forceinline__ float frcp (float x){ return __builtin_amdgcn_rcpf(x); }
// logistic on a PRE-SCALED argument (scale folded into weights/bias).
__device__ __forceinline__ float lgs  (float p){ return frcp(1.0f + fexp2(p)); }
__device__ __forceinline__ float tanh_(float x){ return 1.0f - 2.0f * frcp(1.0f + fexp2(x * 2.8853900817779268f)); }

__device__ __forceinline__ h2v bch(int s){ return __builtin_bit_cast(h2v, s); }
__device__ __forceinline__ float dot8(h8 a, i4 bi, float c){
  const i4 ai = __builtin_bit_cast(i4, a);
  c = __builtin_amdgcn_fdot2(bch(ai.x), bch(bi.x), c, false);
  c = __builtin_amdgcn_fdot2(bch(ai.y), bch(bi.y), c, false);
  c = __builtin_amdgcn_fdot2(bch(ai.z), bch(bi.z), c, false);
  c = __builtin_amdgcn_fdot2(bch(ai.w), bch(bi.w), c, false);
  return c;
}
__device__ __forceinline__ float fdh(int a, int b, float c){
  return __builtin_amdgcn_fdot2(bch(a), bch(b), c, false);
}
__device__ __forceinline__ int pack16(float a, float b){
  h2v p; p.x = (_Float16)a; p.y = (_Float16)b;
  return __builtin_bit_cast(int, p);
}
__device__ __forceinline__ h8 ldh8s(const float* p, float s){
  const f4 a = ((const f4*)p)[0], b = ((const f4*)p)[1];
  h8 r;
  r[0]=(_Float16)(a.x*s); r[1]=(_Float16)(a.y*s); r[2]=(_Float16)(a.z*s); r[3]=(_Float16)(a.w*s);
  r[4]=(_Float16)(b.x*s); r[5]=(_Float16)(b.y*s); r[6]=(_Float16)(b.z*s); r[7]=(_Float16)(b.w*s);
  return r;
}

extern "C" __global__ __launch_bounds__(64, 1) void lstm_enc_kernel(
    const float* __restrict__ x,
    const float* __restrict__ Wih1, const float* __restrict__ Whh1,
    const float* __restrict__ bih1, const float* __restrict__ bhh1,
    const float* __restrict__ Wih2, const float* __restrict__ Whh2,
    const float* __restrict__ bih2, const float* __restrict__ bhh2,
    const float* __restrict__ Wfc,  const float* __restrict__ bfc,
    float* __restrict__ out)
{
    const int l = threadIdx.x;        // 0..63, single wave per block
    const int b = blockIdx.x;         // batch element

    __shared__ __align__(16) _Float16 ring[128][64];   // h1 ring, 16 KB
    __shared__ __align__(16) _Float16 h2r[2][32];      // h2 slots (tau&1)
    __shared__ int xs[2][64];                          // packed-fp16 x, dbuf

    const float kSs = -1.4426950408889634f;   // sigmoid pre-scale
    const float kSg = -2.8853900817779268f;   // tanh-form pre-scale

    // ---- L1 weights: lane l = unit l; 32 h8 resident ----
    const int ri = l, rf = 64 + l, rg = 128 + l, ro = 192 + l;
    h8 wi[8], wf[8], wg[8], wo[8];
    #pragma unroll
    for (int j = 0; j < 8; ++j) {
        wi[j] = ldh8s(Whh1 + ri*64 + j*8, kSs);
        wf[j] = ldh8s(Whh1 + rf*64 + j*8, kSs);
        wg[j] = ldh8s(Whh1 + rg*64 + j*8, kSg);
        wo[j] = ldh8s(Whh1 + ro*64 + j*8, kSs);
    }
    const int wxi = pack16(Wih1[ri*2]*kSs, Wih1[ri*2+1]*kSs);
    const int wxf = pack16(Wih1[rf*2]*kSs, Wih1[rf*2+1]*kSs);
    const int wxg = pack16(Wih1[rg*2]*kSg, Wih1[rg*2+1]*kSg);
    const int wxo = pack16(Wih1[ro*2]*kSs, Wih1[ro*2+1]*kSs);
    const float bi_ = (bih1[ri] + bhh1[ri]) * kSs;
    const float bf_ = (bih1[rf] + bhh1[rf]) * kSs;
    const float bg_ = (bih1[rg] + bhh1[rg]) * kSg;
    const float bo_ = (bih1[ro] + bhh1[ro]) * kSs;

    // ---- L2 weights: lane = (u, hf); rows (i,f) | (g,o); 24 h8 resident ----
    const int u = l & 31, hf = l >> 5;
    const float hff = (float)hf;
    const int rA = hf * 64 + u;        // i (hf=0) or g (hf=1)
    const int rB = hf * 64 + 32 + u;   // f (hf=0) or o (hf=1)
    const float kA = hf ? kSg : kSs;
    h8 wa[12], wb[12];
    #pragma unroll
    for (int j = 0; j < 8; ++j) {
        wa[j] = ldh8s(Wih2 + rA*64 + j*8, kA);
        wb[j] = ldh8s(Wih2 + rB*64 + j*8, kSs);
    }
    #pragma unroll
    for (int j = 0; j < 4; ++j) {
        wa[8+j] = ldh8s(Whh2 + rA*32 + j*8, kA);
        wb[8+j] = ldh8s(Whh2 + rB*32 + j*8, kSs);
    }
    const float ba_ = (bih2[rA] + bhh2[rA]) * kA;
    const float bb_ = (bih2[rB] + bhh2[rB]) * kSs;

    // ---- init: h1(-1)=0 (ring row 127), h2(-1)=0 (slot 1), x chunk 0 ----
    if (l < 32) ((int*)&ring[127][0])[l] = 0;
    if (l < 16) ((int*)&h2r[1][0])[l] = 0;
    const float2* xb2 = (const float2*)(x + (size_t)b * (TT * 2));
    {
        const float2 c0 = xb2[l];
        xs[0][l] = pack16(c0.x, c0.y);
    }
    float2 vxn = xb2[64 + l];          // chunk 1 held in regs

    float cc = 0.f;   // c1 of unit l
    float c2 = 0.f;   // c2 of unit u (half-redundant)

    const i4* rd = (const i4*)&ring[0][0];      // 8 i4 per ring row
    _Float16* rw = &ring[0][0];
    const i4* g0 = (const i4*)&h2r[0][0];
    const i4* g1 = (const i4*)&h2r[1][0];
    _Float16* q0 = &h2r[0][0];
    _Float16* q1 = &h2r[1][0];

    // L1 step: read ring row PR, write row CR, packed x XV (op order = R16)
#define L1S(PR, CR, XV) { \
    const i4* Hp = rd + (PR)*8; \
    i4 H[8]; \
    _Pragma("unroll") for (int j = 0; j < 8; ++j) H[j] = Hp[j]; \
    float ai = bi_, af = bf_, ag = bg_, ao = bo_; \
    _Pragma("unroll") for (int j = 0; j < 8; ++j) { \
        ai = dot8(wi[j], H[j], ai); af = dot8(wf[j], H[j], af); \
        ag = dot8(wg[j], H[j], ag); ao = dot8(wo[j], H[j], ao); } \
    const int xv_ = (XV); \
    ai = fdh(wxi, xv_, ai); af = fdh(wxf, xv_, af); \
    ag = fdh(wxg, xv_, ag); ao = fdh(wxo, xv_, ao); \
    const float gi = lgs(ai), gf = lgs(af), go = lgs(ao); \
    const float gg = fmaf(2.f, lgs(ag), -1.f); \
    cc = fmaf(gf, cc, gi * gg); \
    rw[(CR)*64 + l] = (_Float16)(go * tanh_(cc)); }

    // L2 step: read ring row RR + gate slot GR, write slot QW (op order = R16)
#define L2S(RR, GR, QW) { \
    const i4* Hp = rd + (RR)*8; \
    i4 H[8]; \
    _Pragma("unroll") for (int j = 0; j < 8; ++j) H[j] = Hp[j]; \
    i4 G[4]; \
    _Pragma("unroll") for (int j = 0; j < 4; ++j) G[j] = (GR)[j]; \
    float pa = ba_, pb = bb_; \
    _Pragma("unroll") for (int j = 0; j < 8; ++j) { \
        pa = dot8(wa[j], H[j], pa); pb = dot8(wb[j], H[j], pb); } \
    _Pragma("unroll") for (int j = 0; j < 4; ++j) { \
        pa = dot8(wa[8+j], G[j], pa); pb = dot8(wb[8+j], G[j], pb); } \
    const float sa = lgs(pa); \
    const float va = fmaf(hff, sa - 1.f, sa);   /* i or tanh-g */ \
    const float vb = lgs(pb);                   /* f or o      */ \
    const float oa = __shfl_xor(va, 32); \
    const float ob = __shfl_xor(vb, 32); \
    const float gi2 = hf ? oa : va, gf2 = hf ? ob : vb; \
    const float gg2 = hf ? va : oa, go2 = hf ? vb : ob; \
    c2 = fmaf(gf2, c2, gi2 * gg2); \
    const float h2n = go2 * tanh_(c2); \
    if (!hf) (QW)[u] = (_Float16)h2n; }

    // ---- chunk 0: L1 only (L2 lags one chunk) ----
    {
        const int* xc = xs[0];
        #pragma unroll 1
        for (int s = 0; s < 64; s += 2) {
            L1S((s + 127) & 127, s,     xc[s])
            L1S(s,               s + 1, xc[s + 1])
        }
    }

    // ---- chunks 1..63: interleave L1(chunk c) with L2(chunk c-1) ----
    #pragma unroll 1
    for (int c = 1; c < NCH; ++c) {
        // stage chunk c (held in vxn), prefetch chunk c+1
        xs[c & 1][l] = pack16(vxn.x, vxn.y);
        if (c + 1 < NCH) vxn = xb2[(c + 1) * 64 + l];
        const int* xc = xs[c & 1];
        const int b1 = (c & 1) << 6;   // ring base, L1 chunk c
        const int b2 = b1 ^ 64;        // ring base, L2 chunk c-1
        #pragma unroll 1
        for (int s = 0; s < 64; s += 2) {
            // tau2 = (c-1)*64+s: even -> read slot1, write slot0
            L1S((b1 + s + 127) & 127, b1 + s,     xc[s])
            L2S(b2 + s,     g1, q0)
            L1S(b1 + s,               b1 + s + 1, xc[s + 1])
            L2S(b2 + s + 1, g0, q1)
        }
    }

    // ---- tail: L2 chunk 63 (ring rows 64..127) ----
    {
        #pragma unroll 1
        for (int s = 0; s < 64; s += 2) {
            L2S(64 + s,     g1, q0)
            L2S(64 + s + 1, g0, q1)
        }
    }
#undef L1S
#undef L2S

    // final h2(TT-1): t=4095 odd -> slot 1
    if (l < 16) {
        float sum = bfc[l];
        const float* wr = Wfc + l * 32;
        #pragma unroll
        for (int k = 0; k < 32; ++k) sum = fmaf(wr[k], (float)h2r[1][k], sum);
        out[b * 16 + l] = sum;
    }
}

extern "C" void kernel_launch(void* const* d_in, const int* in_sizes, int n_in,
                              void* d_out, int out_size, void* d_ws, size_t ws_size,
                              hipStream_t stream) {
    const float* x    = (const float*)d_in[0];
    const float* Wih1 = (const float*)d_in[1];
    const float* Whh1 = (const float*)d_in[2];
    const float* bih1 = (const float*)d_in[3];
    const float* bhh1 = (const float*)d_in[4];
    const float* Wih2 = (const float*)d_in[5];
    const float* Whh2 = (const float*)d_in[6];
    const float* bih2 = (const float*)d_in[7];
    const float* bhh2 = (const float*)d_in[8];
    const float* Wfc  = (const float*)d_in[9];
    const float* bfc  = (const float*)d_in[10];

    hipLaunchKernelGGL(lstm_enc_kernel, dim3(BB), dim3(64), 0, stream,
        x, Wih1, Whh1, bih1, bhh1, Wih2, Whh2, bih2, bhh2, Wfc, bfc,
        (float*)d_out);
}

// Round 6
// 1694.276 us; speedup vs baseline: 2.9730x; 2.9730x over previous
//
#include <hip/hip_runtime.h>

// Encoder: 2-layer LSTM (H1=64, H2=32, IN=2), B=512, T=4096, + FC [32->16].
// R18 = R16 (best: 1556us) structure, with the dot-product dependency chain
// cut 4x on both waves (latency, not issue):
//  - each gate row's K-accumulation is split into 4 INDEPENDENT partials
//    (L1: 2+2+2+2 dot8; L2: 3+3+2+4 dot8, h2-slot dots isolated in the
//    last partial since G arrives after H) and tree-summed. Dep depth per
//    gate: 32 serial fdot2 (~200cy) -> ~9 fdot2 + 2 adds (~70cy).
//  - x-dot + bias seeds the first partial BEFORE the H dots so the early
//    chain issues while the broadcast ds_reads land.
//  - everything else verbatim R16: one wave owns all of L1 (lane=unit,
//    K=64), one wave owns all of L2 (lane=(unit,half), K=96, one
//    __shfl_xor(32) exchange), 128-step h1 ring, 1 barrier per 64-step
//    chunk (65 total), pre-scaled gates, block=256={L1,L2}x2 be, grid 256.
// R17 lesson: two LDS-latency chains fused on ONE wave serialize (compiler
// preserves program order at high VGPR) -> keep chains on separate waves.

#define TT 4096
#define BB 512
#define NCH 64   // chunks of 64 steps

typedef float    f4  __attribute__((ext_vector_type(4)));
typedef int      i4  __attribute__((ext_vector_type(4)));
typedef _Float16 h2v __attribute__((ext_vector_type(2)));
typedef _Float16 h8  __attribute__((ext_vector_type(8)));   // 4 VGPRs

__device__ __forceinline__ float fexp2(float x){ return __builtin_amdgcn_exp2f(x); }
__device__ __forceinline__ float frcp (float x){ return __builtin_amdgcn_rcpf(x); }
// logistic on a PRE-SCALED argument (scale folded into weights/bias).
__device__ __forceinline__ float lgs  (float p){ return frcp(1.0f + fexp2(p)); }
__device__ __forceinline__ float tanh_(float x){ return 1.0f - 2.0f * frcp(1.0f + fexp2(x * 2.8853900817779268f)); }

// Lightweight barrier: LDS-drain only; leaves global prefetch in flight.
#define BARRIER() asm volatile("s_waitcnt lgkmcnt(0)\n\ts_barrier" ::: "memory")

__device__ __forceinline__ h2v bch(int s){ return __builtin_bit_cast(h2v, s); }
__device__ __forceinline__ float dot8(h8 a, i4 bi, float c){
  const i4 ai = __builtin_bit_cast(i4, a);
  c = __builtin_amdgcn_fdot2(bch(ai.x), bch(bi.x), c, false);
  c = __builtin_amdgcn_fdot2(bch(ai.y), bch(bi.y), c, false);
  c = __builtin_amdgcn_fdot2(bch(ai.z), bch(bi.z), c, false);
  c = __builtin_amdgcn_fdot2(bch(ai.w), bch(bi.w), c, false);
  return c;
}
__device__ __forceinline__ float fdh(int a, int b, float c){
  return __builtin_amdgcn_fdot2(bch(a), bch(b), c, false);
}
__device__ __forceinline__ int pack16(float a, float b){
  h2v p; p.x = (_Float16)a; p.y = (_Float16)b;
  return __builtin_bit_cast(int, p);
}
__device__ __forceinline__ h8 ldh8s(const float* p, float s){
  const f4 a = ((const f4*)p)[0], b = ((const f4*)p)[1];
  h8 r;
  r[0]=(_Float16)(a.x*s); r[1]=(_Float16)(a.y*s); r[2]=(_Float16)(a.z*s); r[3]=(_Float16)(a.w*s);
  r[4]=(_Float16)(b.x*s); r[5]=(_Float16)(b.y*s); r[6]=(_Float16)(b.z*s); r[7]=(_Float16)(b.w*s);
  return r;
}

extern "C" __global__ __launch_bounds__(256, 1) void lstm_enc_kernel(
    const float* __restrict__ x,
    const float* __restrict__ Wih1, const float* __restrict__ Whh1,
    const float* __restrict__ bih1, const float* __restrict__ bhh1,
    const float* __restrict__ Wih2, const float* __restrict__ Whh2,
    const float* __restrict__ bih2, const float* __restrict__ bhh2,
    const float* __restrict__ Wfc,  const float* __restrict__ bfc,
    float* __restrict__ out)
{
    const int tid = threadIdx.x;
    const int l   = tid & 63;
    const int wv  = __builtin_amdgcn_readfirstlane(tid >> 6);   // 0..3
    const int be  = wv >> 1;                   // batch element in block
    const bool isL1 = ((wv & 1) == 0);         // waves 0,2 = L1; 1,3 = L2
    const int bg  = blockIdx.x * 2 + be;       // global batch index

    // h1 ring: 128 steps (2 chunks x 64), row t%128 = h1(t) as 64 fp16.
    __shared__ __align__(16) _Float16 ring[2][128][64];   // 32 KB
    __shared__ __align__(16) _Float16 h2r[2][2][32];      // h2 slots (t&1)
    __shared__ int xs[2][2][64];                          // packed-fp16 x

    const float kSs = -1.4426950408889634f;   // sigmoid pre-scale
    const float kSg = -2.8853900817779268f;   // tanh-form pre-scale

    if (isL1) {
        // ------------------- L1 wave: lane u = l owns unit u -------------------
        h8 wi[8], wf[8], wg[8], wo[8];
        const int ri = l, rf = 64 + l, rg = 128 + l, ro = 192 + l;
        #pragma unroll
        for (int j = 0; j < 8; ++j) {
            wi[j] = ldh8s(Whh1 + ri*64 + j*8, kSs);
            wf[j] = ldh8s(Whh1 + rf*64 + j*8, kSs);
            wg[j] = ldh8s(Whh1 + rg*64 + j*8, kSg);
            wo[j] = ldh8s(Whh1 + ro*64 + j*8, kSs);
        }
        const int wxi = pack16(Wih1[ri*2]*kSs, Wih1[ri*2+1]*kSs);
        const int wxf = pack16(Wih1[rf*2]*kSs, Wih1[rf*2+1]*kSs);
        const int wxg = pack16(Wih1[rg*2]*kSg, Wih1[rg*2+1]*kSg);
        const int wxo = pack16(Wih1[ro*2]*kSs, Wih1[ro*2+1]*kSs);
        const float bi_ = (bih1[ri] + bhh1[ri]) * kSs;
        const float bf_ = (bih1[rf] + bhh1[rf]) * kSs;
        const float bg_ = (bih1[rg] + bhh1[rg]) * kSg;
        const float bo_ = (bih1[ro] + bhh1[ro]) * kSs;

        if (l < 32) ((int*)&ring[be][127][0])[l] = 0;   // h1(-1) = 0
        BARRIER();

        float cc = 0.f;
        _Float16* rw = &ring[be][0][0];
        const i4* rd = (const i4*)&ring[be][0][0];      // 8 i4 per row

// 4 independent partials per gate (dep depth 32 -> ~9 fdot2), x+bias seeds
// the first partial so its chain runs while the broadcast reads land.
#define L1S(PR, CR, XV) { \
    const i4* Hp = rd + (PR)*8; \
    i4 H[8]; \
    _Pragma("unroll") for (int j = 0; j < 8; ++j) H[j] = Hp[j]; \
    const int xv_ = (XV); \
    float ai = fdh(wxi, xv_, bi_), af = fdh(wxf, xv_, bf_); \
    float ag = fdh(wxg, xv_, bg_), ao = fdh(wxo, xv_, bo_); \
    ai = dot8(wi[0],H[0],ai); ai = dot8(wi[1],H[1],ai); \
    af = dot8(wf[0],H[0],af); af = dot8(wf[1],H[1],af); \
    ag = dot8(wg[0],H[0],ag); ag = dot8(wg[1],H[1],ag); \
    ao = dot8(wo[0],H[0],ao); ao = dot8(wo[1],H[1],ao); \
    float pi1 = dot8(wi[2],H[2],0.f); pi1 = dot8(wi[3],H[3],pi1); \
    float pf1 = dot8(wf[2],H[2],0.f); pf1 = dot8(wf[3],H[3],pf1); \
    float pg1 = dot8(wg[2],H[2],0.f); pg1 = dot8(wg[3],H[3],pg1); \
    float po1 = dot8(wo[2],H[2],0.f); po1 = dot8(wo[3],H[3],po1); \
    float pi2 = dot8(wi[4],H[4],0.f); pi2 = dot8(wi[5],H[5],pi2); \
    float pf2 = dot8(wf[4],H[4],0.f); pf2 = dot8(wf[5],H[5],pf2); \
    float pg2 = dot8(wg[4],H[4],0.f); pg2 = dot8(wg[5],H[5],pg2); \
    float po2 = dot8(wo[4],H[4],0.f); po2 = dot8(wo[5],H[5],po2); \
    float pi3 = dot8(wi[6],H[6],0.f); pi3 = dot8(wi[7],H[7],pi3); \
    float pf3 = dot8(wf[6],H[6],0.f); pf3 = dot8(wf[7],H[7],pf3); \
    float pg3 = dot8(wg[6],H[6],0.f); pg3 = dot8(wg[7],H[7],pg3); \
    float po3 = dot8(wo[6],H[6],0.f); po3 = dot8(wo[7],H[7],po3); \
    ai = (ai + pi1) + (pi2 + pi3); \
    af = (af + pf1) + (pf2 + pf3); \
    ag = (ag + pg1) + (pg2 + pg3); \
    ao = (ao + po1) + (po2 + po3); \
    const float gi = lgs(ai), gf = lgs(af), go = lgs(ao); \
    const float gg = fmaf(2.f, lgs(ag), -1.f); \
    cc = fmaf(gf, cc, gi * gg); \
    rw[(CR)*64 + l] = (_Float16)(go * tanh_(cc)); }

        #pragma unroll 1
        for (int c = 0; c <= NCH; ++c) {
            if (c < NCH) {
                const int base = (c & 1) * 64;
                const int p0 = (base ^ 64) + 63;   // last row of other chunk
                const int* xc = xs[be][c & 1];
                L1S(p0, base, xc[0])
                #pragma unroll 2
                for (int s = 1; s < 64; ++s) { L1S(base + s - 1, base + s, xc[s]) }
            }
            BARRIER();
        }
#undef L1S
    } else {
        // --------- L2 wave: lane = (u = l&31, hf = l>>5); rows (i,f)|(g,o) ---------
        const int u = l & 31, hf = l >> 5;
        const float hff = (float)hf;
        const int rA = hf * 64 + u;        // i (hf=0) or g (hf=1)
        const int rB = hf * 64 + 32 + u;   // f (hf=0) or o (hf=1)
        const float kA = hf ? kSg : kSs;
        h8 wa[12], wb[12];
        #pragma unroll
        for (int j = 0; j < 8; ++j) {
            wa[j] = ldh8s(Wih2 + rA*64 + j*8, kA);
            wb[j] = ldh8s(Wih2 + rB*64 + j*8, kSs);
        }
        #pragma unroll
        for (int j = 0; j < 4; ++j) {
            wa[8+j] = ldh8s(Whh2 + rA*32 + j*8, kA);
            wb[8+j] = ldh8s(Whh2 + rB*32 + j*8, kSs);
        }
        const float ba_ = (bih2[rA] + bhh2[rA]) * kA;
        const float bb_ = (bih2[rB] + bhh2[rB]) * kSs;

        if (l < 16) ((int*)&h2r[be][1][0])[l] = 0;      // h2(-1) = 0
        // stage x chunk 0, prefetch chunk 1
        const float2* xb2 = (const float2*)(x + (size_t)bg * (TT * 2));
        {
            const float2 c0 = xb2[l];
            xs[be][0][l] = pack16(c0.x, c0.y);
        }
        float2 vxn = xb2[64 + l];
        BARRIER();

        float c2 = 0.f;
        const i4* rdh = (const i4*)&ring[be][0][0];
        const i4* g0 = (const i4*)&h2r[be][0][0];
        const i4* g1 = (const i4*)&h2r[be][1][0];
        _Float16* q0 = &h2r[be][0][0];
        _Float16* q1 = &h2r[be][1][0];

// 4 partials per row (3+3+2+4 dot8); the h2-slot (G) dots isolated in the
// last partial since G reads are issued after H reads (arrive later).
#define L2S(S, GR, QW) { \
    const i4* Hp = rc + (S)*8; \
    i4 H[8]; \
    _Pragma("unroll") for (int j = 0; j < 8; ++j) H[j] = Hp[j]; \
    i4 G[4]; \
    _Pragma("unroll") for (int j = 0; j < 4; ++j) G[j] = (GR)[j]; \
    float pa = dot8(wa[0],H[0],ba_); pa = dot8(wa[1],H[1],pa); pa = dot8(wa[2],H[2],pa); \
    float pb = dot8(wb[0],H[0],bb_); pb = dot8(wb[1],H[1],pb); pb = dot8(wb[2],H[2],pb); \
    float pa1 = dot8(wa[3],H[3],0.f); pa1 = dot8(wa[4],H[4],pa1); pa1 = dot8(wa[5],H[5],pa1); \
    float pb1 = dot8(wb[3],H[3],0.f); pb1 = dot8(wb[4],H[4],pb1); pb1 = dot8(wb[5],H[5],pb1); \
    float pa2 = dot8(wa[6],H[6],0.f); pa2 = dot8(wa[7],H[7],pa2); \
    float pb2 = dot8(wb[6],H[6],0.f); pb2 = dot8(wb[7],H[7],pb2); \
    float pa3 = dot8(wa[8],G[0],0.f); pa3 = dot8(wa[9],G[1],pa3); \
    pa3 = dot8(wa[10],G[2],pa3); pa3 = dot8(wa[11],G[3],pa3); \
    float pb3 = dot8(wb[8],G[0],0.f); pb3 = dot8(wb[9],G[1],pb3); \
    pb3 = dot8(wb[10],G[2],pb3); pb3 = dot8(wb[11],G[3],pb3); \
    pa = (pa + pa1) + (pa2 + pa3); \
    pb = (pb + pb1) + (pb2 + pb3); \
    const float sa = lgs(pa); \
    const float va = fmaf(hff, sa - 1.f, sa);   /* i or tanh-g */ \
    const float vb = lgs(pb);                   /* f or o      */ \
    const float oa = __shfl_xor(va, 32); \
    const float ob = __shfl_xor(vb, 32); \
    const float gi = hf ? oa : va, gf = hf ? ob : vb; \
    const float gg = hf ? va : oa, go = hf ? vb : ob; \
    c2 = fmaf(gf, c2, gi * gg); \
    const float h2n = go * tanh_(c2); \
    if (!hf) (QW)[u] = (_Float16)h2n; }

        #pragma unroll 1
        for (int c = 0; c <= NCH; ++c) {
            // stage chunk c+1 (in vxn), prefetch chunk c+2
            if (c + 1 < NCH) xs[be][(c + 1) & 1][l] = pack16(vxn.x, vxn.y);
            if (c + 2 < NCH) vxn = xb2[(c + 2) * 64 + l];
            if (c > 0) {
                const i4* rc = rdh + ((c - 1) & 1) * 64 * 8;   // chunk c-1 rows
                // tau = (c-1)*64 + s; tau even: write slot0, read slot1
                for (int s = 0; s < 64; s += 2) {
                    L2S(s,     g1, q0)
                    L2S(s + 1, g0, q1)
                }
            }
            BARRIER();
        }
#undef L2S

        // final h2(TT-1) in h2r[be][1] (4095 is odd -> slot 1)
        if (l < 16) {
            float sum = bfc[l];
            const float* wr = Wfc + l * 32;
            #pragma unroll
            for (int k = 0; k < 32; ++k) sum = fmaf(wr[k], (float)h2r[be][1][k], sum);
            out[bg * 16 + l] = sum;
        }
    }
}

extern "C" void kernel_launch(void* const* d_in, const int* in_sizes, int n_in,
                              void* d_out, int out_size, void* d_ws, size_t ws_size,
                              hipStream_t stream) {
    const float* x    = (const float*)d_in[0];
    const float* Wih1 = (const float*)d_in[1];
    const float* Whh1 = (const float*)d_in[2];
    const float* bih1 = (const float*)d_in[3];
    const float* bhh1 = (const float*)d_in[4];
    const float* Wih2 = (const float*)d_in[5];
    const float* Whh2 = (const float*)d_in[6];
    const float* bih2 = (const float*)d_in[7];
    const float* bhh2 = (const float*)d_in[8];
    const float* Wfc  = (const float*)d_in[9];
    const float* bfc  = (const float*)d_in[10];

    hipLaunchKernelGGL(lstm_enc_kernel, dim3(BB / 2), dim3(256), 0, stream,
        x, Wih1, Whh1, bih1, bhh1, Wih2, Whh2, bih2, bhh2, Wfc, bfc,
        (float*)d_out);
}